// Round 7
// baseline (1412.903 us; speedup 1.0000x reference)
//
#include <hip/hip_runtime.h>
#include <hip/hip_bf16.h>

#define USER_N   100000
#define ITEM_N   200000
#define N_NODES  300000           // USER_N + ITEM_N
#define LATDIM   64
#define N_EDGES  9600000
#define N_LAYERS 3

// coarse bucket = row >> 12  (4096 rows ~= 1MB colval region)
#define CSHIFT   12
#define CROWS    4096
#define NCOARSE  ((N_NODES + CROWS - 1) / CROWS)   // 74
#define NCPAD    80                                 // multiple of 8
#define SUBS     64                                 // passB blocks per coarse
#define CHUNK    4096                               // passA chunk
#define NCHUNKS  ((N_EDGES + CHUNK - 1) / CHUNK)    // 2344

// ---- bf16 helpers (RNE) ----
__device__ __forceinline__ unsigned short f2bf(float f) {
    unsigned int u = __float_as_uint(f);
    u += 0x7FFFu + ((u >> 16) & 1u);
    return (unsigned short)(u >> 16);
}
__device__ __forceinline__ float bf2f(unsigned short h) {
    return __uint_as_float(((unsigned int)h) << 16);
}

// ---------------------------------------------------------------------------
// convert concat(u,i) fp32 -> bf16 cur0
// ---------------------------------------------------------------------------
__global__ void cvt_concat_kernel(const float* __restrict__ u,
                                  const float* __restrict__ it,
                                  ushort4* __restrict__ cur0,
                                  int n4u, int n4total) {
    int stride = gridDim.x * blockDim.x;
    for (int i = blockIdx.x * blockDim.x + threadIdx.x; i < n4total; i += stride) {
        float4 v = (i < n4u) ? ((const float4*)u)[i]
                             : ((const float4*)it)[i - n4u];
        ushort4 o;
        o.x = f2bf(v.x); o.y = f2bf(v.y); o.z = f2bf(v.z); o.w = f2bf(v.w);
        cur0[i] = o;
    }
}

// ---------------------------------------------------------------------------
// row histogram (300K counters, 1.2MB L2-resident)
// ---------------------------------------------------------------------------
__global__ void hist_row_kernel(const int* __restrict__ row,
                                int* __restrict__ counts) {
    int stride = gridDim.x * blockDim.x;
    for (int e = blockIdx.x * blockDim.x + threadIdx.x; e < N_EDGES; e += stride)
        atomicAdd(&counts[row[e]], 1);
}

// ---------------------------------------------------------------------------
// per-coarse-bucket sums of row counts
// ---------------------------------------------------------------------------
__global__ void coarse_sum_kernel(const int* __restrict__ counts,
                                  int* __restrict__ csum) {
    __shared__ int lds[1024];
    int c = blockIdx.x, t = threadIdx.x;
    int base = c * CROWS;
    int s = 0;
    #pragma unroll
    for (int k = 0; k < 4; ++k) {
        int i = base + t + k * 1024;
        if (i < N_NODES) s += counts[i];
    }
    lds[t] = s;
    __syncthreads();
    for (int off = 512; off > 0; off >>= 1) {
        if (t < off) lds[t] += lds[t + off];
        __syncthreads();
    }
    if (t == 0) csum[c] = lds[0];
}

// ---------------------------------------------------------------------------
// exclusive scan of NCOARSE sums -> cbase, cursorA
// ---------------------------------------------------------------------------
__global__ void scan_coarse_kernel(const int* __restrict__ csum,
                                   int* __restrict__ cbase,
                                   int* __restrict__ cursorA,
                                   int* __restrict__ rowPtr) {
    __shared__ int lds[128];
    int t = threadIdx.x;
    int v = (t < NCOARSE) ? csum[t] : 0;
    lds[t] = v;
    __syncthreads();
    for (int off = 1; off < 128; off <<= 1) {
        int add = (t >= off) ? lds[t - off] : 0;
        __syncthreads();
        lds[t] += add;
        __syncthreads();
    }
    if (t < NCOARSE) { int ex = lds[t] - v; cbase[t] = ex; cursorA[t] = ex; }
    if (t == NCOARSE - 1) cbase[NCOARSE] = lds[t];
    if (t == 0) rowPtr[N_NODES] = N_EDGES;
}

// ---------------------------------------------------------------------------
// within-coarse scan of 4096 row counts -> rowPtr, rowCur
// ---------------------------------------------------------------------------
__global__ void scan_rows_kernel(const int* __restrict__ counts,
                                 const int* __restrict__ cbase,
                                 int* __restrict__ rowPtr,
                                 int* __restrict__ rowCur) {
    __shared__ int lds[1024];
    int c = blockIdx.x, t = threadIdx.x;
    int base = c * CROWS + t * 4;
    int v0 = 0, v1 = 0, v2 = 0, v3 = 0;
    if (base     < N_NODES) v0 = counts[base];
    if (base + 1 < N_NODES) v1 = counts[base + 1];
    if (base + 2 < N_NODES) v2 = counts[base + 2];
    if (base + 3 < N_NODES) v3 = counts[base + 3];
    int s = v0 + v1 + v2 + v3;
    lds[t] = s;
    __syncthreads();
    for (int off = 1; off < 1024; off <<= 1) {
        int add = (t >= off) ? lds[t - off] : 0;
        __syncthreads();
        lds[t] += add;
        __syncthreads();
    }
    int ex = cbase[c] + lds[t] - s;
    if (base     < N_NODES) { rowPtr[base]     = ex; rowCur[base]     = ex; } ex += v0;
    if (base + 1 < N_NODES) { rowPtr[base + 1] = ex; rowCur[base + 1] = ex; } ex += v1;
    if (base + 2 < N_NODES) { rowPtr[base + 2] = ex; rowCur[base + 2] = ex; } ex += v2;
    if (base + 3 < N_NODES) { rowPtr[base + 3] = ex; rowCur[base + 3] = ex; }
}

// ---------------------------------------------------------------------------
// passA: chunked coarse partition. LDS-stage 4096 edges, hist 74, reserve a
// run per coarse via one global atomic, scatter. Runs ~440B; frontier/block
// = 74 x ~2 lines -> L2-merged writes.
// key = row_local12 << 19 | col19
// ---------------------------------------------------------------------------
__global__ __launch_bounds__(256)
void passA_kernel(const int*   __restrict__ row,
                  const int*   __restrict__ col,
                  const float* __restrict__ val,
                  int*         __restrict__ cursorA,
                  int2*        __restrict__ tempA) {
    __shared__ int2 stage[CHUNK];             // 32 KB
    __shared__ unsigned char cb[CHUNK];       // 4 KB
    __shared__ int h[NCOARSE];
    __shared__ int cur[NCOARSE];
    int t = threadIdx.x;
    for (int cid = blockIdx.x; cid < NCHUNKS; cid += gridDim.x) {
        if (t < NCOARSE) h[t] = 0;
        __syncthreads();
        int e0 = cid * CHUNK;
        int e1 = e0 + CHUNK; if (e1 > N_EDGES) e1 = N_EDGES;
        for (int e = e0 + t; e < e1; e += 256) {
            int r = row[e];
            int c = r >> CSHIFT;
            stage[e - e0] = make_int2(((r & (CROWS - 1)) << 19) | col[e],
                                      __float_as_int(val[e]));
            cb[e - e0] = (unsigned char)c;
            atomicAdd(&h[c], 1);
        }
        __syncthreads();
        if (t < NCOARSE) {
            int n = h[t];
            cur[t] = n ? atomicAdd(&cursorA[t], n) : 0;
        }
        __syncthreads();
        for (int e = e0 + t; e < e1; e += 256) {
            int c = cb[e - e0];
            int pos = atomicAdd(&cur[c], 1);
            tempA[pos] = stage[e - e0];
        }
        __syncthreads();
    }
}

// ---------------------------------------------------------------------------
// passB: per-coarse row scatter to final colval via rowCur. All SUBS blocks
// of a coarse bucket land on one XCD (blk%8) and coarse buckets are
// sequenced per XCD -> active 1MB region is L2-resident, writes merge.
// ---------------------------------------------------------------------------
__global__ __launch_bounds__(256)
void passB_kernel(const int*  __restrict__ cbase,
                  const int2* __restrict__ tempA,
                  int*        __restrict__ rowCur,
                  int2*       __restrict__ colval) {
    int blk = blockIdx.x;
    int x = blk & 7;
    int j = blk >> 3;
    int s = j & (SUBS - 1);
    int c = (j >> 6) * 8 + x;
    if (c >= NCOARSE) return;
    int beg = cbase[c], end = cbase[c + 1];
    int n = end - beg;
    int q = (n + SUBS - 1) / SUBS;
    int i0 = beg + s * q;
    int i1 = i0 + q; if (i1 > end) i1 = end;
    int rbase = c << CSHIFT;
    for (int i = i0 + threadIdx.x; i < i1; i += 256) {
        int2 kv = tempA[i];
        int r = rbase + (((unsigned)kv.x) >> 19);
        int pos = atomicAdd(&rowCur[r], 1);
        colval[pos] = make_int2(kv.x & 0x7FFFF, kv.y);
    }
}

// ---------------------------------------------------------------------------
// bf16 CSR SpMM: 16 lanes/row, lane q owns dims [4q,4q+4). 8 gathers in flight
// ---------------------------------------------------------------------------
__global__ void spmm_bf16_kernel(const int*  __restrict__ rp,
                                 const int2* __restrict__ cv,
                                 const ushort4* __restrict__ x4,
                                 ushort4*       __restrict__ y4) {
    int g = (blockIdx.x * blockDim.x + threadIdx.x) >> 4;   // row
    if (g >= N_NODES) return;
    int q = threadIdx.x & 15;
    int beg = rp[g];
    int end = rp[g + 1];

    float s0 = 0.f, s1 = 0.f, s2 = 0.f, s3 = 0.f;
    int i = beg;
    for (; i + 8 <= end; i += 8) {
        int2 cc[8]; ushort4 gg[8];
        #pragma unroll
        for (int k = 0; k < 8; ++k) cc[k] = cv[i + k];
        #pragma unroll
        for (int k = 0; k < 8; ++k) gg[k] = x4[(size_t)cc[k].x * 16 + q];
        #pragma unroll
        for (int k = 0; k < 8; ++k) {
            float v = __int_as_float(cc[k].y);
            s0 += bf2f(gg[k].x) * v; s1 += bf2f(gg[k].y) * v;
            s2 += bf2f(gg[k].z) * v; s3 += bf2f(gg[k].w) * v;
        }
    }
    for (; i < end; ++i) {
        int2 cc = cv[i];
        ushort4 gg = x4[(size_t)cc.x * 16 + q];
        float v = __int_as_float(cc.y);
        s0 += bf2f(gg.x) * v; s1 += bf2f(gg.y) * v;
        s2 += bf2f(gg.z) * v; s3 += bf2f(gg.w) * v;
    }

    ushort4 o;
    o.x = f2bf(s0); o.y = f2bf(s1); o.z = f2bf(s2); o.w = f2bf(s3);
    y4[(size_t)g * 16 + q] = o;
}

// ---------------------------------------------------------------------------
// final: acc = concat(u,i) + c1 + c2 + c3   (bf16 -> fp32)
// ---------------------------------------------------------------------------
__global__ void final_acc_kernel(const float* __restrict__ u,
                                 const float* __restrict__ it,
                                 const ushort4* __restrict__ c1,
                                 const ushort4* __restrict__ c2,
                                 const ushort4* __restrict__ c3,
                                 float4* __restrict__ acc,
                                 int n4u, int n4total) {
    int stride = gridDim.x * blockDim.x;
    for (int i = blockIdx.x * blockDim.x + threadIdx.x; i < n4total; i += stride) {
        float4 e = (i < n4u) ? ((const float4*)u)[i]
                             : ((const float4*)it)[i - n4u];
        ushort4 a = c1[i], b = c2[i], c = c3[i];
        e.x += bf2f(a.x) + bf2f(b.x) + bf2f(c.x);
        e.y += bf2f(a.y) + bf2f(b.y) + bf2f(c.y);
        e.z += bf2f(a.z) + bf2f(b.z) + bf2f(c.z);
        e.w += bf2f(a.w) + bf2f(b.w) + bf2f(c.w);
        acc[i] = e;
    }
}

// ---------------------------------------------------------------------------
// Fallback path: fp32 COO atomic SpMM + acc add (used if ws too small)
// ---------------------------------------------------------------------------
__global__ void copy_concat_kernel(const float* __restrict__ u,
                                   const float* __restrict__ it,
                                   float* __restrict__ cur,
                                   float* __restrict__ acc,
                                   int n4u, int n4total) {
    int stride = gridDim.x * blockDim.x;
    for (int i = blockIdx.x * blockDim.x + threadIdx.x; i < n4total; i += stride) {
        float4 v = (i < n4u) ? ((const float4*)u)[i]
                             : ((const float4*)it)[i - n4u];
        ((float4*)cur)[i] = v;
        ((float4*)acc)[i] = v;
    }
}

__global__ void spmm_atomic_kernel(const int*   __restrict__ row,
                                   const int*   __restrict__ col,
                                   const float* __restrict__ val,
                                   const float* __restrict__ x,
                                   float*       __restrict__ y) {
    const int total = N_EDGES * 16;
    int stride = gridDim.x * blockDim.x;
    for (int t = blockIdx.x * blockDim.x + threadIdx.x; t < total; t += stride) {
        int e = t >> 4;
        int q = t & 15;
        int r = row[e];
        int c = col[e];
        float v = val[e];
        float4 g = ((const float4*)x)[c * 16 + q];
        float* yp = y + r * 64 + q * 4;
        atomicAdd(yp + 0, g.x * v);
        atomicAdd(yp + 1, g.y * v);
        atomicAdd(yp + 2, g.z * v);
        atomicAdd(yp + 3, g.w * v);
    }
}

__global__ void acc_add_kernel(float* __restrict__ acc,
                               const float* __restrict__ add,
                               int n4) {
    int stride = gridDim.x * blockDim.x;
    for (int i = blockIdx.x * blockDim.x + threadIdx.x; i < n4; i += stride) {
        float4 a = ((const float4*)acc)[i];
        float4 b = ((const float4*)add)[i];
        a.x += b.x; a.y += b.y; a.z += b.z; a.w += b.w;
        ((float4*)acc)[i] = a;
    }
}

extern "C" void kernel_launch(void* const* d_in, const int* in_sizes, int n_in,
                              void* d_out, int out_size, void* d_ws, size_t ws_size,
                              hipStream_t stream) {
    const float* uEmb = (const float*)d_in[0];
    const float* iEmb = (const float*)d_in[1];
    const int*   row  = (const int*)  d_in[2];
    const int*   col  = (const int*)  d_in[3];
    const float* val  = (const float*)d_in[4];

    float* acc = (float*)d_out;

    const int n4total = N_NODES * (LATDIM / 4);       // 4.8M groups of 4
    const int n4u     = USER_N  * (LATDIM / 4);
    const size_t embBytes  = (size_t)N_NODES * LATDIM * sizeof(float);
    const size_t embBytesH = (size_t)N_NODES * LATDIM * 2;   // 38.4MB

    const int BLK = 256;
    const int GRID_MEM = 2048;

    // ---- workspace layout ----
    auto align256 = [](size_t x) { return (x + 255) & ~(size_t)255; };
    size_t off = 0;
    size_t o_cur0   = off; off += align256(embBytesH);
    size_t o_c1     = off; off += align256(embBytesH);   // tempA = c1+c2
    size_t o_c2     = off; off += align256(embBytesH);
    size_t o_c3     = off; off += align256(embBytesH);
    size_t o_colval = off; off += align256((size_t)N_EDGES * 8);
    size_t o_rowptr = off; off += align256(((size_t)N_NODES + 1) * 4);
    size_t o_rowcur = off; off += align256((size_t)N_NODES * 4);
    size_t o_counts = off; off += align256((size_t)N_NODES * 4);
    size_t o_csum   = off; off += align256((size_t)NCOARSE * 4);
    size_t o_cbase  = off; off += align256(((size_t)NCOARSE + 1) * 4);
    size_t o_cursA  = off; off += align256((size_t)NCOARSE * 4);
    size_t needed = off;

    char* wsb = (char*)d_ws;

    if (ws_size >= needed) {
        // ============ hierarchical bf16 CSR path ============
        ushort4* cur0 = (ushort4*)(wsb + o_cur0);
        ushort4* c1   = (ushort4*)(wsb + o_c1);
        ushort4* c2   = (ushort4*)(wsb + o_c2);
        ushort4* c3   = (ushort4*)(wsb + o_c3);
        int2* colval  = (int2*)(wsb + o_colval);
        int2* tempA   = (int2*)(wsb + o_c1);     // aliases c1+c2, dead after passB
        int* rowPtr   = (int*)(wsb + o_rowptr);
        int* rowCur   = (int*)(wsb + o_rowcur);
        int* counts   = (int*)(wsb + o_counts);
        int* csum     = (int*)(wsb + o_csum);
        int* cbase    = (int*)(wsb + o_cbase);
        int* cursorA  = (int*)(wsb + o_cursA);

        cvt_concat_kernel<<<GRID_MEM, BLK, 0, stream>>>(uEmb, iEmb, cur0,
                                                        n4u, n4total);

        hipMemsetAsync(counts, 0, (size_t)N_NODES * 4, stream);
        hist_row_kernel  <<<GRID_MEM, BLK, 0, stream>>>(row, counts);
        coarse_sum_kernel<<<NCOARSE, 1024, 0, stream>>>(counts, csum);
        scan_coarse_kernel<<<1, 128, 0, stream>>>(csum, cbase, cursorA, rowPtr);
        scan_rows_kernel <<<NCOARSE, 1024, 0, stream>>>(counts, cbase,
                                                        rowPtr, rowCur);
        passA_kernel<<<1024, 256, 0, stream>>>(row, col, val, cursorA, tempA);
        passB_kernel<<<8 * SUBS * (NCPAD / 8), 256, 0, stream>>>(cbase, tempA,
                                                                 rowCur, colval);

        const int GRID_SPMM = (N_NODES * 16 + BLK - 1) / BLK;   // 18750
        spmm_bf16_kernel<<<GRID_SPMM, BLK, 0, stream>>>(rowPtr, colval, cur0, c1);
        spmm_bf16_kernel<<<GRID_SPMM, BLK, 0, stream>>>(rowPtr, colval, c1,   c2);
        spmm_bf16_kernel<<<GRID_SPMM, BLK, 0, stream>>>(rowPtr, colval, c2,   c3);

        final_acc_kernel<<<GRID_MEM, BLK, 0, stream>>>(uEmb, iEmb, c1, c2, c3,
                                                       (float4*)acc,
                                                       n4u, n4total);
    } else {
        // ============ fallback: fp32 atomic path ============
        float* cur = (float*)wsb;
        float* nxt = (float*)(wsb + embBytes);
        copy_concat_kernel<<<GRID_MEM, BLK, 0, stream>>>(uEmb, iEmb, cur, acc,
                                                         n4u, n4total);
        for (int l = 0; l < N_LAYERS; ++l) {
            hipMemsetAsync(nxt, 0, embBytes, stream);
            spmm_atomic_kernel<<<4096, BLK, 0, stream>>>(row, col, val, cur, nxt);
            acc_add_kernel<<<GRID_MEM, BLK, 0, stream>>>(acc, nxt, n4total);
            float* t = cur; cur = nxt; nxt = t;
        }
    }
}

// Round 8
// 878.263 us; speedup vs baseline: 1.6087x; 1.6087x over previous
//
#include <hip/hip_runtime.h>
#include <hip/hip_bf16.h>

#define USER_N   100000
#define ITEM_N   200000
#define N_NODES  300000           // USER_N + ITEM_N
#define LATDIM   64
#define N_EDGES  9600000
#define N_LAYERS 3

// coarse bucket = row >> 11  (2048 rows ~= 523KB colval region)
#define CSHIFT   11
#define CROWS    2048
#define NCOARSE  ((N_NODES + CROWS - 1) / CROWS)   // 147
#define CHUNK    4096                               // passA chunk
#define NCHUNKS  ((N_EDGES + CHUNK - 1) / CHUNK)    // 2344
#define GPA      512                                // passA grid

// ---- bf16 helpers (RNE) ----
__device__ __forceinline__ unsigned short f2bf(float f) {
    unsigned int u = __float_as_uint(f);
    u += 0x7FFFu + ((u >> 16) & 1u);
    return (unsigned short)(u >> 16);
}
__device__ __forceinline__ float bf2f(unsigned short h) {
    return __uint_as_float(((unsigned int)h) << 16);
}

// ---------------------------------------------------------------------------
// convert concat(u,i) fp32 -> bf16 cur0
// ---------------------------------------------------------------------------
__global__ void cvt_concat_kernel(const float* __restrict__ u,
                                  const float* __restrict__ it,
                                  ushort4* __restrict__ cur0,
                                  int n4u, int n4total) {
    int stride = gridDim.x * blockDim.x;
    for (int i = blockIdx.x * blockDim.x + threadIdx.x; i < n4total; i += stride) {
        float4 v = (i < n4u) ? ((const float4*)u)[i]
                             : ((const float4*)it)[i - n4u];
        ushort4 o;
        o.x = f2bf(v.x); o.y = f2bf(v.y); o.z = f2bf(v.z); o.w = f2bf(v.w);
        cur0[i] = o;
    }
}

// ---------------------------------------------------------------------------
// h1: coarse histogram — per-block LDS hist, 147 global merges per block.
// NO per-edge global atomics (write-through-to-HBM on this chip).
// ---------------------------------------------------------------------------
__global__ void h1_kernel(const int* __restrict__ row, int* __restrict__ ccnt) {
    __shared__ int h[NCOARSE];
    int t = threadIdx.x;
    if (t < NCOARSE) h[t] = 0;
    __syncthreads();
    int stride = gridDim.x * blockDim.x;
    for (int e = blockIdx.x * blockDim.x + t; e < N_EDGES; e += stride)
        atomicAdd(&h[row[e] >> CSHIFT], 1);
    __syncthreads();
    if (t < NCOARSE && h[t]) atomicAdd(&ccnt[t], h[t]);
}

// ---------------------------------------------------------------------------
// scan of NCOARSE totals -> cbase, cursorA; rowPtr[N]=E
// ---------------------------------------------------------------------------
__global__ void scan_coarse_kernel(const int* __restrict__ ccnt,
                                   int* __restrict__ cbase,
                                   int* __restrict__ cursorA,
                                   int* __restrict__ rowPtr) {
    __shared__ int lds[256];
    int t = threadIdx.x;
    int v = (t < NCOARSE) ? ccnt[t] : 0;
    lds[t] = v;
    __syncthreads();
    for (int off = 1; off < 256; off <<= 1) {
        int add = (t >= off) ? lds[t - off] : 0;
        __syncthreads();
        lds[t] += add;
        __syncthreads();
    }
    if (t < NCOARSE) { int ex = lds[t] - v; cbase[t] = ex; cursorA[t] = ex; }
    if (t == NCOARSE - 1) cbase[NCOARSE] = lds[t];
    if (t == 0) rowPtr[N_NODES] = N_EDGES;
}

// ---------------------------------------------------------------------------
// passA: chunked coarse partition. LDS-stage 4096 edges, LDS hist 147,
// reserve one run per coarse per chunk (1 global atomic each), scatter runs
// (~224B) contiguously. key = row_local(11b)<<19 | col(19b)
// ---------------------------------------------------------------------------
__global__ __launch_bounds__(256)
void passA_kernel(const int*   __restrict__ row,
                  const int*   __restrict__ col,
                  const float* __restrict__ val,
                  int*         __restrict__ cursorA,
                  int2*        __restrict__ tempA) {
    __shared__ int2 stage[CHUNK];             // 32 KB
    __shared__ unsigned char cb[CHUNK];       // 4 KB
    __shared__ int h[NCOARSE];
    __shared__ int cur[NCOARSE];
    int t = threadIdx.x;
    for (int cid = blockIdx.x; cid < NCHUNKS; cid += gridDim.x) {
        if (t < NCOARSE) h[t] = 0;
        __syncthreads();
        int e0 = cid * CHUNK;
        int e1 = e0 + CHUNK; if (e1 > N_EDGES) e1 = N_EDGES;
        for (int e = e0 + t; e < e1; e += 256) {
            int r = row[e];
            int c = r >> CSHIFT;
            stage[e - e0] = make_int2(((r & (CROWS - 1)) << 19) | col[e],
                                      __float_as_int(val[e]));
            cb[e - e0] = (unsigned char)c;
            atomicAdd(&h[c], 1);
        }
        __syncthreads();
        if (t < NCOARSE) {
            int n = h[t];
            cur[t] = n ? atomicAdd(&cursorA[t], n) : 0;
        }
        __syncthreads();
        for (int e = e0 + t; e < e1; e += 256) {
            int c = cb[e - e0];
            int pos = atomicAdd(&cur[c], 1);
            tempA[pos] = stage[e - e0];
        }
        __syncthreads();
    }
}

// ---------------------------------------------------------------------------
// passB: one 1024-thread block per coarse bucket. LDS hist of 2048 rows,
// LDS scan (emits rowPtr slice), LDS-cursor scatter into the bucket's
// exclusive ~523KB colval region (L2-resident; no global atomics).
// ---------------------------------------------------------------------------
__global__ __launch_bounds__(1024)
void passB_kernel(const int*  __restrict__ cbase,
                  const int2* __restrict__ tempA,
                  int2*       __restrict__ colval,
                  int*        __restrict__ rowPtr) {
    __shared__ int hist[CROWS];     // 8 KB
    __shared__ int psum[1024];      // 4 KB
    __shared__ int curs[CROWS];     // 8 KB
    int c = blockIdx.x;
    int t = threadIdx.x;
    int beg = cbase[c], end = cbase[c + 1];

    hist[t] = 0; hist[t + 1024] = 0;
    __syncthreads();
    for (int i = beg + t; i < end; i += 1024)
        atomicAdd(&hist[((unsigned)tempA[i].x) >> 19], 1);
    __syncthreads();

    int b0 = hist[2 * t], b1 = hist[2 * t + 1];
    int tot = b0 + b1;
    psum[t] = tot;
    __syncthreads();
    for (int off = 1; off < 1024; off <<= 1) {
        int add = (t >= off) ? psum[t - off] : 0;
        __syncthreads();
        psum[t] += add;
        __syncthreads();
    }
    int ex = psum[t] - tot;              // exclusive over pairs
    int j0 = 2 * t, j1 = 2 * t + 1;
    int e0 = beg + ex, e1 = beg + ex + b0;
    curs[j0] = e0;
    curs[j1] = e1;
    int gr0 = c * CROWS + j0;
    int gr1 = c * CROWS + j1;
    if (gr0 < N_NODES) rowPtr[gr0] = e0;
    if (gr1 < N_NODES) rowPtr[gr1] = e1;
    __syncthreads();

    for (int i = beg + t; i < end; i += 1024) {
        int2 kv = tempA[i];
        int rl = ((unsigned)kv.x) >> 19;
        int pos = atomicAdd(&curs[rl], 1);
        colval[pos] = make_int2(kv.x & 0x7FFFF, kv.y);
    }
}

// ---------------------------------------------------------------------------
// bf16 CSR SpMM: 16 lanes/row, lane q owns dims [4q,4q+4). 8 gathers in flight
// ---------------------------------------------------------------------------
__global__ void spmm_bf16_kernel(const int*  __restrict__ rp,
                                 const int2* __restrict__ cv,
                                 const ushort4* __restrict__ x4,
                                 ushort4*       __restrict__ y4) {
    int g = (blockIdx.x * blockDim.x + threadIdx.x) >> 4;   // row
    if (g >= N_NODES) return;
    int q = threadIdx.x & 15;
    int beg = rp[g];
    int end = rp[g + 1];

    float s0 = 0.f, s1 = 0.f, s2 = 0.f, s3 = 0.f;
    int i = beg;
    for (; i + 8 <= end; i += 8) {
        int2 cc[8]; ushort4 gg[8];
        #pragma unroll
        for (int k = 0; k < 8; ++k) cc[k] = cv[i + k];
        #pragma unroll
        for (int k = 0; k < 8; ++k) gg[k] = x4[(size_t)cc[k].x * 16 + q];
        #pragma unroll
        for (int k = 0; k < 8; ++k) {
            float v = __int_as_float(cc[k].y);
            s0 += bf2f(gg[k].x) * v; s1 += bf2f(gg[k].y) * v;
            s2 += bf2f(gg[k].z) * v; s3 += bf2f(gg[k].w) * v;
        }
    }
    for (; i < end; ++i) {
        int2 cc = cv[i];
        ushort4 gg = x4[(size_t)cc.x * 16 + q];
        float v = __int_as_float(cc.y);
        s0 += bf2f(gg.x) * v; s1 += bf2f(gg.y) * v;
        s2 += bf2f(gg.z) * v; s3 += bf2f(gg.w) * v;
    }

    ushort4 o;
    o.x = f2bf(s0); o.y = f2bf(s1); o.z = f2bf(s2); o.w = f2bf(s3);
    y4[(size_t)g * 16 + q] = o;
}

// ---------------------------------------------------------------------------
// final: acc = concat(u,i) + c1 + c2 + c3   (bf16 -> fp32)
// ---------------------------------------------------------------------------
__global__ void final_acc_kernel(const float* __restrict__ u,
                                 const float* __restrict__ it,
                                 const ushort4* __restrict__ c1,
                                 const ushort4* __restrict__ c2,
                                 const ushort4* __restrict__ c3,
                                 float4* __restrict__ acc,
                                 int n4u, int n4total) {
    int stride = gridDim.x * blockDim.x;
    for (int i = blockIdx.x * blockDim.x + threadIdx.x; i < n4total; i += stride) {
        float4 e = (i < n4u) ? ((const float4*)u)[i]
                             : ((const float4*)it)[i - n4u];
        ushort4 a = c1[i], b = c2[i], c = c3[i];
        e.x += bf2f(a.x) + bf2f(b.x) + bf2f(c.x);
        e.y += bf2f(a.y) + bf2f(b.y) + bf2f(c.y);
        e.z += bf2f(a.z) + bf2f(b.z) + bf2f(c.z);
        e.w += bf2f(a.w) + bf2f(b.w) + bf2f(c.w);
        acc[i] = e;
    }
}

// ---------------------------------------------------------------------------
// Fallback path: fp32 COO atomic SpMM + acc add (used if ws too small)
// ---------------------------------------------------------------------------
__global__ void copy_concat_kernel(const float* __restrict__ u,
                                   const float* __restrict__ it,
                                   float* __restrict__ cur,
                                   float* __restrict__ acc,
                                   int n4u, int n4total) {
    int stride = gridDim.x * blockDim.x;
    for (int i = blockIdx.x * blockDim.x + threadIdx.x; i < n4total; i += stride) {
        float4 v = (i < n4u) ? ((const float4*)u)[i]
                             : ((const float4*)it)[i - n4u];
        ((float4*)cur)[i] = v;
        ((float4*)acc)[i] = v;
    }
}

__global__ void spmm_atomic_kernel(const int*   __restrict__ row,
                                   const int*   __restrict__ col,
                                   const float* __restrict__ val,
                                   const float* __restrict__ x,
                                   float*       __restrict__ y) {
    const int total = N_EDGES * 16;
    int stride = gridDim.x * blockDim.x;
    for (int t = blockIdx.x * blockDim.x + threadIdx.x; t < total; t += stride) {
        int e = t >> 4;
        int q = t & 15;
        int r = row[e];
        int c = col[e];
        float v = val[e];
        float4 g = ((const float4*)x)[c * 16 + q];
        float* yp = y + r * 64 + q * 4;
        atomicAdd(yp + 0, g.x * v);
        atomicAdd(yp + 1, g.y * v);
        atomicAdd(yp + 2, g.z * v);
        atomicAdd(yp + 3, g.w * v);
    }
}

__global__ void acc_add_kernel(float* __restrict__ acc,
                               const float* __restrict__ add,
                               int n4) {
    int stride = gridDim.x * blockDim.x;
    for (int i = blockIdx.x * blockDim.x + threadIdx.x; i < n4; i += stride) {
        float4 a = ((const float4*)acc)[i];
        float4 b = ((const float4*)add)[i];
        a.x += b.x; a.y += b.y; a.z += b.z; a.w += b.w;
        ((float4*)acc)[i] = a;
    }
}

extern "C" void kernel_launch(void* const* d_in, const int* in_sizes, int n_in,
                              void* d_out, int out_size, void* d_ws, size_t ws_size,
                              hipStream_t stream) {
    const float* uEmb = (const float*)d_in[0];
    const float* iEmb = (const float*)d_in[1];
    const int*   row  = (const int*)  d_in[2];
    const int*   col  = (const int*)  d_in[3];
    const float* val  = (const float*)d_in[4];

    float* acc = (float*)d_out;

    const int n4total = N_NODES * (LATDIM / 4);       // 4.8M groups of 4
    const int n4u     = USER_N  * (LATDIM / 4);
    const size_t embBytes  = (size_t)N_NODES * LATDIM * sizeof(float);
    const size_t embBytesH = (size_t)N_NODES * LATDIM * 2;   // 38.4MB

    const int BLK = 256;
    const int GRID_MEM = 2048;

    // ---- workspace layout ----
    auto align256 = [](size_t x) { return (x + 255) & ~(size_t)255; };
    size_t off = 0;
    size_t o_cur0   = off; off += align256(embBytesH);
    size_t o_c1     = off; off += align256(embBytesH);   // tempA = c1+c2
    size_t o_c2     = off; off += align256(embBytesH);
    size_t o_c3     = off; off += align256(embBytesH);
    size_t o_colval = off; off += align256((size_t)N_EDGES * 8);
    size_t o_rowptr = off; off += align256(((size_t)N_NODES + 1) * 4);
    size_t o_ccnt   = off; off += align256((size_t)NCOARSE * 4);
    size_t o_cbase  = off; off += align256(((size_t)NCOARSE + 1) * 4);
    size_t o_cursA  = off; off += align256((size_t)NCOARSE * 4);
    size_t needed = off;

    char* wsb = (char*)d_ws;

    if (ws_size >= needed) {
        // ============ hierarchical bf16 CSR path ============
        ushort4* cur0 = (ushort4*)(wsb + o_cur0);
        ushort4* c1   = (ushort4*)(wsb + o_c1);
        ushort4* c2   = (ushort4*)(wsb + o_c2);
        ushort4* c3   = (ushort4*)(wsb + o_c3);
        int2* colval  = (int2*)(wsb + o_colval);
        int2* tempA   = (int2*)(wsb + o_c1);     // aliases c1+c2, dead after passB
        int* rowPtr   = (int*)(wsb + o_rowptr);
        int* ccnt     = (int*)(wsb + o_ccnt);
        int* cbase    = (int*)(wsb + o_cbase);
        int* cursorA  = (int*)(wsb + o_cursA);

        cvt_concat_kernel<<<GRID_MEM, BLK, 0, stream>>>(uEmb, iEmb, cur0,
                                                        n4u, n4total);

        hipMemsetAsync(ccnt, 0, (size_t)NCOARSE * 4, stream);
        h1_kernel<<<GPA, 256, 0, stream>>>(row, ccnt);
        scan_coarse_kernel<<<1, 256, 0, stream>>>(ccnt, cbase, cursorA, rowPtr);
        passA_kernel<<<GPA, 256, 0, stream>>>(row, col, val, cursorA, tempA);
        passB_kernel<<<NCOARSE, 1024, 0, stream>>>(cbase, tempA, colval, rowPtr);

        const int GRID_SPMM = (N_NODES * 16 + BLK - 1) / BLK;   // 18750
        spmm_bf16_kernel<<<GRID_SPMM, BLK, 0, stream>>>(rowPtr, colval, cur0, c1);
        spmm_bf16_kernel<<<GRID_SPMM, BLK, 0, stream>>>(rowPtr, colval, c1,   c2);
        spmm_bf16_kernel<<<GRID_SPMM, BLK, 0, stream>>>(rowPtr, colval, c2,   c3);

        final_acc_kernel<<<GRID_MEM, BLK, 0, stream>>>(uEmb, iEmb, c1, c2, c3,
                                                       (float4*)acc,
                                                       n4u, n4total);
    } else {
        // ============ fallback: fp32 atomic path ============
        float* cur = (float*)wsb;
        float* nxt = (float*)(wsb + embBytes);
        copy_concat_kernel<<<GRID_MEM, BLK, 0, stream>>>(uEmb, iEmb, cur, acc,
                                                         n4u, n4total);
        for (int l = 0; l < N_LAYERS; ++l) {
            hipMemsetAsync(nxt, 0, embBytes, stream);
            spmm_atomic_kernel<<<4096, BLK, 0, stream>>>(row, col, val, cur, nxt);
            acc_add_kernel<<<GRID_MEM, BLK, 0, stream>>>(acc, nxt, n4total);
            float* t = cur; cur = nxt; nxt = t;
        }
    }
}